// Round 1
// baseline (1516.354 us; speedup 1.0000x reference)
//
#include <hip/hip_runtime.h>
#include <hip/hip_bf16.h>
#include <math.h>

#define N_NODES 50000
#define N_EDGES 800000
#define IN_SIZE 256
#define OUT_SIZE 128
#define EDGE_DIM 64

// ---------------- proj GEMM: out[which] = x @ W[which] + b[which] ----------------
// grid.x = ceil(50000/64), grid.y = 4 (q,k,v,skip->aggv). Block 256.
// Tile: 64 rows x 128 cols, K-chunks of 32.
__global__ __launch_bounds__(256) void proj_kernel(
    const float* __restrict__ x,
    const float* __restrict__ Wq, const float* __restrict__ bq,
    const float* __restrict__ Wk, const float* __restrict__ bk,
    const float* __restrict__ Wv, const float* __restrict__ bv,
    const float* __restrict__ Ws, const float* __restrict__ bs,
    float* __restrict__ q, float* __restrict__ k, float* __restrict__ v,
    float* __restrict__ aggv)
{
    const int which = blockIdx.y;
    const float* W = (which == 0) ? Wq : (which == 1) ? Wk : (which == 2) ? Wv : Ws;
    const float* b = (which == 0) ? bq : (which == 1) ? bk : (which == 2) ? bv : bs;
    float* out     = (which == 0) ? q  : (which == 1) ? k  : (which == 2) ? v  : aggv;

    const int m0 = blockIdx.x * 64;
    __shared__ __align__(16) float xs[64][33];   // 64 rows x 32 k (+1 pad)
    __shared__ __align__(16) float ws[32][128];  // 32 k x 128 cols

    const int t  = threadIdx.x;
    const int tx = t & 15;   // col group: cols tx*8 .. tx*8+7
    const int ty = t >> 4;   // row group: rows ty*4 .. ty*4+3

    float acc[4][8];
    #pragma unroll
    for (int i = 0; i < 4; i++)
        #pragma unroll
        for (int j = 0; j < 8; j++) acc[i][j] = 0.f;

    for (int k0 = 0; k0 < IN_SIZE; k0 += 32) {
        // x tile: 64x32 = 512 float4 loads
        #pragma unroll
        for (int i = t; i < 512; i += 256) {
            int r  = i >> 3;
            int c4 = i & 7;
            int gr = m0 + r;
            float4 val = (gr < N_NODES)
                ? ((const float4*)(x + (size_t)gr * IN_SIZE + k0))[c4]
                : make_float4(0.f, 0.f, 0.f, 0.f);
            xs[r][c4 * 4 + 0] = val.x;
            xs[r][c4 * 4 + 1] = val.y;
            xs[r][c4 * 4 + 2] = val.z;
            xs[r][c4 * 4 + 3] = val.w;
        }
        // W tile: 32x128 = 1024 float4 loads
        #pragma unroll
        for (int i = t; i < 1024; i += 256) {
            int r  = i >> 5;
            int c4 = i & 31;
            float4 val = ((const float4*)(W + (size_t)(k0 + r) * OUT_SIZE))[c4];
            ((float4*)&ws[r][0])[c4] = val;
        }
        __syncthreads();
        #pragma unroll
        for (int kk = 0; kk < 32; kk++) {
            float xv[4];
            #pragma unroll
            for (int i = 0; i < 4; i++) xv[i] = xs[ty * 4 + i][kk];
            float wv[8];
            #pragma unroll
            for (int j = 0; j < 8; j++) wv[j] = ws[kk][tx * 8 + j];
            #pragma unroll
            for (int i = 0; i < 4; i++)
                #pragma unroll
                for (int j = 0; j < 8; j++)
                    acc[i][j] = fmaf(xv[i], wv[j], acc[i][j]);
        }
        __syncthreads();
    }
    #pragma unroll
    for (int i = 0; i < 4; i++) {
        int gr = m0 + ty * 4 + i;
        if (gr >= N_NODES) continue;
        #pragma unroll
        for (int j = 0; j < 8; j++) {
            int c = tx * 8 + j;
            out[(size_t)gr * OUT_SIZE + c] = acc[i][j] + b[c];
        }
    }
}

// ---------------- q2 = q @ We^T ; qb = q . be ----------------
// one wave per node, 4 waves per block
__global__ __launch_bounds__(256) void q2_kernel(
    const float* __restrict__ q, const float* __restrict__ We,
    const float* __restrict__ be, float* __restrict__ q2, float* __restrict__ qb)
{
    int node = blockIdx.x * 4 + (threadIdx.x >> 6);
    int lane = threadIdx.x & 63;
    if (node >= N_NODES) return;
    const float* qr = q + (size_t)node * OUT_SIZE;
    // q2[node][lane] = sum_c qr[c] * We[lane][c]
    const float* wr = We + (size_t)lane * OUT_SIZE;
    float acc = 0.f;
    #pragma unroll 8
    for (int c = 0; c < OUT_SIZE; c++) acc = fmaf(qr[c], wr[c], acc);
    q2[(size_t)node * EDGE_DIM + lane] = acc;
    // qb
    float p = qr[lane] * be[lane] + qr[lane + 64] * be[lane + 64];
    #pragma unroll
    for (int off = 32; off > 0; off >>= 1) p += __shfl_down(p, off);
    if (lane == 0) qb[node] = p;
}

__device__ __forceinline__ unsigned int enc_f32(float f) {
    unsigned int b = __float_as_uint(f);
    return (b & 0x80000000u) ? ~b : (b | 0x80000000u);
}
__device__ __forceinline__ float dec_f32(unsigned int e) {
    unsigned int b = (e & 0x80000000u) ? (e & 0x7FFFFFFFu) : ~e;
    return __uint_as_float(b);
}

// ---------------- alpha per edge + atomic max ----------------
// one wave per edge, 4 edges per block
__global__ __launch_bounds__(256) void alpha_kernel(
    const int* __restrict__ ei, const float* __restrict__ q,
    const float* __restrict__ k, const float* __restrict__ q2,
    const float* __restrict__ qb, const float* __restrict__ ea,
    float* __restrict__ alpha, unsigned int* __restrict__ m_u)
{
    int e = blockIdx.x * 4 + (threadIdx.x >> 6);
    if (e >= N_EDGES) return;
    int lane = threadIdx.x & 63;
    int src = ei[e];
    int dst = ei[N_EDGES + e];
    const float* qd = q + (size_t)dst * OUT_SIZE;
    const float* ks = k + (size_t)src * OUT_SIZE;
    float p = qd[lane] * ks[lane] + qd[lane + 64] * ks[lane + 64];
    p = fmaf(q2[(size_t)dst * EDGE_DIM + lane], ea[(size_t)e * EDGE_DIM + lane], p);
    #pragma unroll
    for (int off = 32; off > 0; off >>= 1) p += __shfl_down(p, off);
    if (lane == 0) {
        float a = (p + qb[dst]) * 0.08838834764831845f;  // 1/sqrt(128)
        alpha[e] = a;
        atomicMax(m_u + dst, enc_f32(a));
    }
}

// ---------------- exp + atomic sum ----------------
__global__ __launch_bounds__(256) void exp_kernel(
    const int* __restrict__ ei, float* __restrict__ alpha,
    const unsigned int* __restrict__ m_u, float* __restrict__ s)
{
    int e = blockIdx.x * blockDim.x + threadIdx.x;
    if (e >= N_EDGES) return;
    int dst = ei[N_EDGES + e];
    float m = dec_f32(m_u[dst]);
    float a = expf(alpha[e] - m);
    alpha[e] = a;
    atomicAdd(s + dst, a);
}

// ---------------- aggregation: atomics into aggv/agg2/aggA ----------------
// one wave per edge
__global__ __launch_bounds__(256) void agg_kernel(
    const int* __restrict__ ei, const float* __restrict__ v,
    const float* __restrict__ ea, const float* __restrict__ alpha,
    const float* __restrict__ s, float* __restrict__ aggv,
    float* __restrict__ agg2, float* __restrict__ aggA)
{
    int e = blockIdx.x * 4 + (threadIdx.x >> 6);
    if (e >= N_EDGES) return;
    int lane = threadIdx.x & 63;
    int src = ei[e];
    int dst = ei[N_EDGES + e];
    float a = alpha[e] / (s[dst] + 1e-16f);
    const float* vs = v + (size_t)src * OUT_SIZE;
    atomicAdd(&aggv[(size_t)dst * OUT_SIZE + lane],      a * vs[lane]);
    atomicAdd(&aggv[(size_t)dst * OUT_SIZE + lane + 64], a * vs[lane + 64]);
    atomicAdd(&agg2[(size_t)dst * EDGE_DIM + lane], a * ea[(size_t)e * EDGE_DIM + lane]);
    if (lane == 0) atomicAdd(&aggA[dst], a);
}

// ---------------- epilogue: out = elu(aggv + agg2@We + aggA*be) ----------------
// one wave per node
__global__ __launch_bounds__(256) void final_kernel(
    const float* __restrict__ aggv, const float* __restrict__ agg2,
    const float* __restrict__ aggA, const float* __restrict__ We,
    const float* __restrict__ be, float* __restrict__ out)
{
    int node = blockIdx.x * 4 + (threadIdx.x >> 6);
    if (node >= N_NODES) return;
    int lane = threadIdx.x & 63;
    float aA = aggA[node];
    const float* g2 = agg2 + (size_t)node * EDGE_DIM;
    float acc0 = aggv[(size_t)node * OUT_SIZE + lane]      + aA * be[lane];
    float acc1 = aggv[(size_t)node * OUT_SIZE + lane + 64] + aA * be[lane + 64];
    #pragma unroll 8
    for (int d = 0; d < EDGE_DIM; d++) {
        float g = g2[d];
        acc0 = fmaf(g, We[(size_t)d * OUT_SIZE + lane],      acc0);
        acc1 = fmaf(g, We[(size_t)d * OUT_SIZE + lane + 64], acc1);
    }
    acc0 = (acc0 > 0.f) ? acc0 : (expf(acc0) - 1.f);
    acc1 = (acc1 > 0.f) ? acc1 : (expf(acc1) - 1.f);
    out[(size_t)node * OUT_SIZE + lane]      = acc0;
    out[(size_t)node * OUT_SIZE + lane + 64] = acc1;
}

extern "C" void kernel_launch(void* const* d_in, const int* in_sizes, int n_in,
                              void* d_out, int out_size, void* d_ws, size_t ws_size,
                              hipStream_t stream) {
    const float* x   = (const float*)d_in[0];
    const int*   ei  = (const int*)d_in[1];
    const float* ea  = (const float*)d_in[2];
    const float* Wq  = (const float*)d_in[3];
    const float* bq  = (const float*)d_in[4];
    const float* Wk  = (const float*)d_in[5];
    const float* bk  = (const float*)d_in[6];
    const float* Wv  = (const float*)d_in[7];
    const float* bv  = (const float*)d_in[8];
    const float* We  = (const float*)d_in[9];
    const float* be  = (const float*)d_in[10];
    const float* Ws  = (const float*)d_in[11];
    const float* bs  = (const float*)d_in[12];
    float* out = (float*)d_out;

    // workspace layout (floats)
    float* ws0   = (float*)d_ws;
    float* q     = ws0;                           // 6,400,000
    float* k     = q   + (size_t)N_NODES * OUT_SIZE;   // 6,400,000
    float* v     = k   + (size_t)N_NODES * OUT_SIZE;   // 6,400,000
    float* aggv  = v   + (size_t)N_NODES * OUT_SIZE;   // 6,400,000 (skip + messages)
    float* q2    = aggv + (size_t)N_NODES * OUT_SIZE;  // 3,200,000
    float* qb    = q2  + (size_t)N_NODES * EDGE_DIM;   // 50,000
    float* alpha = qb  + N_NODES;                      // 800,000
    float* agg2  = alpha + N_EDGES;                    // 3,200,000  -- zeroed below
    float* aggA  = agg2 + (size_t)N_NODES * EDGE_DIM;  // 50,000
    float* s     = aggA + N_NODES;                     // 50,000
    unsigned int* m_u = (unsigned int*)(s + N_NODES);  // 50,000

    // zero [agg2 .. m_u] in one shot: 3,200,000 + 3*50,000 elements
    size_t zero_elems = (size_t)N_NODES * EDGE_DIM + 3 * (size_t)N_NODES;
    hipMemsetAsync(agg2, 0, zero_elems * sizeof(float), stream);

    dim3 gProj((N_NODES + 63) / 64, 4);
    proj_kernel<<<gProj, 256, 0, stream>>>(x, Wq, bq, Wk, bk, Wv, bv, Ws, bs,
                                           q, k, v, aggv);
    q2_kernel<<<N_NODES / 4, 256, 0, stream>>>(q, We, be, q2, qb);
    alpha_kernel<<<N_EDGES / 4, 256, 0, stream>>>(ei, q, k, q2, qb, ea, alpha, m_u);
    exp_kernel<<<N_EDGES / 256, 256, 0, stream>>>(ei, alpha, m_u, s);
    agg_kernel<<<N_EDGES / 4, 256, 0, stream>>>(ei, v, ea, alpha, s, aggv, agg2, aggA);
    final_kernel<<<N_NODES / 4, 256, 0, stream>>>(aggv, agg2, aggA, We, be, out);
}

// Round 2
// 970.222 us; speedup vs baseline: 1.5629x; 1.5629x over previous
//
#include <hip/hip_runtime.h>
#include <hip/hip_bf16.h>
#include <math.h>

#define N_NODES 50000
#define N_EDGES 800000
#define IN_SIZE 256
#define OUT_SIZE 128
#define EDGE_DIM 64

#define SCAN_B 256
#define NBLK ((N_NODES + SCAN_B - 1) / SCAN_B)   // 196

// ---------------- proj GEMM: out[which] = x @ W[which] + b[which] ----------------
__global__ __launch_bounds__(256) void proj_kernel(
    const float* __restrict__ x,
    const float* __restrict__ Wq, const float* __restrict__ bq,
    const float* __restrict__ Wk, const float* __restrict__ bk,
    const float* __restrict__ Wv, const float* __restrict__ bv,
    const float* __restrict__ Ws, const float* __restrict__ bs,
    float* __restrict__ q, float* __restrict__ k, float* __restrict__ v,
    float* __restrict__ sk)
{
    const int which = blockIdx.y;
    const float* W = (which == 0) ? Wq : (which == 1) ? Wk : (which == 2) ? Wv : Ws;
    const float* b = (which == 0) ? bq : (which == 1) ? bk : (which == 2) ? bv : bs;
    float* out     = (which == 0) ? q  : (which == 1) ? k  : (which == 2) ? v  : sk;

    const int m0 = blockIdx.x * 64;
    __shared__ __align__(16) float xs[64][33];
    __shared__ __align__(16) float ws[32][128];

    const int t  = threadIdx.x;
    const int tx = t & 15;
    const int ty = t >> 4;

    float acc[4][8];
    #pragma unroll
    for (int i = 0; i < 4; i++)
        #pragma unroll
        for (int j = 0; j < 8; j++) acc[i][j] = 0.f;

    for (int k0 = 0; k0 < IN_SIZE; k0 += 32) {
        #pragma unroll
        for (int i = t; i < 512; i += 256) {
            int r  = i >> 3;
            int c4 = i & 7;
            int gr = m0 + r;
            float4 val = (gr < N_NODES)
                ? ((const float4*)(x + (size_t)gr * IN_SIZE + k0))[c4]
                : make_float4(0.f, 0.f, 0.f, 0.f);
            xs[r][c4 * 4 + 0] = val.x;
            xs[r][c4 * 4 + 1] = val.y;
            xs[r][c4 * 4 + 2] = val.z;
            xs[r][c4 * 4 + 3] = val.w;
        }
        #pragma unroll
        for (int i = t; i < 1024; i += 256) {
            int r  = i >> 5;
            int c4 = i & 31;
            float4 val = ((const float4*)(W + (size_t)(k0 + r) * OUT_SIZE))[c4];
            ((float4*)&ws[r][0])[c4] = val;
        }
        __syncthreads();
        #pragma unroll
        for (int kk = 0; kk < 32; kk++) {
            float xv[4];
            #pragma unroll
            for (int i = 0; i < 4; i++) xv[i] = xs[ty * 4 + i][kk];
            float wv[8];
            #pragma unroll
            for (int j = 0; j < 8; j++) wv[j] = ws[kk][tx * 8 + j];
            #pragma unroll
            for (int i = 0; i < 4; i++)
                #pragma unroll
                for (int j = 0; j < 8; j++)
                    acc[i][j] = fmaf(xv[i], wv[j], acc[i][j]);
        }
        __syncthreads();
    }
    #pragma unroll
    for (int i = 0; i < 4; i++) {
        int gr = m0 + ty * 4 + i;
        if (gr >= N_NODES) continue;
        #pragma unroll
        for (int j = 0; j < 8; j++) {
            int c = tx * 8 + j;
            out[(size_t)gr * OUT_SIZE + c] = acc[i][j] + b[c];
        }
    }
}

// ---------------- q2 = q @ We^T ; qb = q . be ----------------
__global__ __launch_bounds__(256) void q2_kernel(
    const float* __restrict__ q, const float* __restrict__ We,
    const float* __restrict__ be, float* __restrict__ q2, float* __restrict__ qb)
{
    int node = blockIdx.x * 4 + (threadIdx.x >> 6);
    int lane = threadIdx.x & 63;
    if (node >= N_NODES) return;
    const float* qr = q + (size_t)node * OUT_SIZE;
    const float* wr = We + (size_t)lane * OUT_SIZE;
    float acc = 0.f;
    #pragma unroll 8
    for (int c = 0; c < OUT_SIZE; c++) acc = fmaf(qr[c], wr[c], acc);
    q2[(size_t)node * EDGE_DIM + lane] = acc;
    float p = qr[lane] * be[lane] + qr[lane + 64] * be[lane + 64];
    #pragma unroll
    for (int off = 32; off > 0; off >>= 1) p += __shfl_down(p, off);
    if (lane == 0) qb[node] = p;
}

// ---------------- CSR build ----------------
__global__ __launch_bounds__(256) void hist_kernel(
    const int* __restrict__ ei, int* __restrict__ counts)
{
    int e = blockIdx.x * 256 + threadIdx.x;
    if (e >= N_EDGES) return;
    atomicAdd(&counts[ei[N_EDGES + e]], 1);
}

__global__ __launch_bounds__(SCAN_B) void scan1_kernel(
    const int* __restrict__ counts, int* __restrict__ incl, int* __restrict__ bsum)
{
    __shared__ int tmp[SCAN_B];
    int i = blockIdx.x * SCAN_B + threadIdx.x;
    int val = (i < N_NODES) ? counts[i] : 0;
    tmp[threadIdx.x] = val;
    __syncthreads();
    for (int off = 1; off < SCAN_B; off <<= 1) {
        int t = (threadIdx.x >= off) ? tmp[threadIdx.x - off] : 0;
        __syncthreads();
        tmp[threadIdx.x] += t;
        __syncthreads();
    }
    if (i < N_NODES) incl[i] = tmp[threadIdx.x];
    if (threadIdx.x == SCAN_B - 1) bsum[blockIdx.x] = tmp[SCAN_B - 1];
}

__global__ __launch_bounds__(SCAN_B) void scan2_kernel(int* __restrict__ bsum)
{
    __shared__ int tmp[SCAN_B];
    int val = (threadIdx.x < NBLK) ? bsum[threadIdx.x] : 0;
    tmp[threadIdx.x] = val;
    __syncthreads();
    for (int off = 1; off < SCAN_B; off <<= 1) {
        int t = (threadIdx.x >= off) ? tmp[threadIdx.x - off] : 0;
        __syncthreads();
        tmp[threadIdx.x] += t;
        __syncthreads();
    }
    if (threadIdx.x < NBLK) bsum[threadIdx.x] = tmp[threadIdx.x];
}

__global__ __launch_bounds__(SCAN_B) void scan3_kernel(
    const int* __restrict__ incl, const int* __restrict__ bsum,
    const int* __restrict__ counts, int* __restrict__ rowptr, int* __restrict__ cursor)
{
    int i = blockIdx.x * SCAN_B + threadIdx.x;
    if (i >= N_NODES) return;
    int off = (blockIdx.x == 0) ? 0 : bsum[blockIdx.x - 1];
    int inc = incl[i] + off;
    rowptr[i + 1] = inc;
    cursor[i] = inc - counts[i];
    if (i == 0) rowptr[0] = 0;
}

__global__ __launch_bounds__(256) void scatter_kernel(
    const int* __restrict__ ei, int* __restrict__ cursor,
    int* __restrict__ csr_src, int* __restrict__ csr_eid)
{
    int e = blockIdx.x * 256 + threadIdx.x;
    if (e >= N_EDGES) return;
    int dst = ei[N_EDGES + e];
    int pos = atomicAdd(&cursor[dst], 1);
    csr_src[pos] = ei[e];
    csr_eid[pos] = e;
}

// ---------------- fused per-dst-node: score + softmax + aggregate + epilogue ----------------
// one wave per node, 4 waves per block
__global__ __launch_bounds__(256) void fused_kernel(
    const int* __restrict__ rowptr, const int* __restrict__ csr_src,
    const int* __restrict__ csr_eid,
    const float* __restrict__ q, const float* __restrict__ k,
    const float* __restrict__ v, const float* __restrict__ q2,
    const float* __restrict__ qb, const float* __restrict__ ea,
    const float* __restrict__ sk, const float* __restrict__ We,
    const float* __restrict__ be, float* __restrict__ out)
{
    int node = blockIdx.x * 4 + (threadIdx.x >> 6);
    if (node >= N_NODES) return;
    int lane = threadIdx.x & 63;
    int beg = rowptr[node];
    int end = rowptr[node + 1];

    float q0  = q[(size_t)node * OUT_SIZE + lane];
    float q1  = q[(size_t)node * OUT_SIZE + lane + 64];
    float q2v = q2[(size_t)node * EDGE_DIM + lane];
    float qbv = qb[node];

    float m = -INFINITY, l = 0.f;
    float acc0 = 0.f, acc1 = 0.f, acc2 = 0.f;

    for (int i = beg; i < end; i++) {
        int src = csr_src[i];
        int e   = csr_eid[i];
        float eav = ea[(size_t)e * EDGE_DIM + lane];
        float k0  = k[(size_t)src * OUT_SIZE + lane];
        float k1  = k[(size_t)src * OUT_SIZE + lane + 64];
        float v0  = v[(size_t)src * OUT_SIZE + lane];
        float v1  = v[(size_t)src * OUT_SIZE + lane + 64];
        float p = q0 * k0 + q1 * k1 + q2v * eav;
        #pragma unroll
        for (int off = 32; off > 0; off >>= 1) p += __shfl_xor(p, off);
        float a  = (p + qbv) * 0.08838834764831845f;  // 1/sqrt(128)
        float mn = fmaxf(m, a);
        float sc = __expf(m - mn);   // first iter: exp(-inf)=0
        float pe = __expf(a - mn);
        l    = l * sc + pe;
        acc0 = fmaf(acc0, sc, pe * v0);
        acc1 = fmaf(acc1, sc, pe * v1);
        acc2 = fmaf(acc2, sc, pe * eav);
        m = mn;
    }

    float inv  = 1.f / (l + 1e-16f);
    float aggA = l * inv;      // sum of normalized weights (1, or 0 for deg-0)
    acc0 *= inv; acc1 *= inv; acc2 *= inv;

    float o0 = acc0 + aggA * be[lane]      + sk[(size_t)node * OUT_SIZE + lane];
    float o1 = acc1 + aggA * be[lane + 64] + sk[(size_t)node * OUT_SIZE + lane + 64];
    #pragma unroll 8
    for (int d = 0; d < EDGE_DIM; d++) {
        float g = __shfl(acc2, d);
        o0 = fmaf(g, We[(size_t)d * OUT_SIZE + lane],      o0);
        o1 = fmaf(g, We[(size_t)d * OUT_SIZE + lane + 64], o1);
    }
    o0 = (o0 > 0.f) ? o0 : (__expf(o0) - 1.f);
    o1 = (o1 > 0.f) ? o1 : (__expf(o1) - 1.f);
    out[(size_t)node * OUT_SIZE + lane]      = o0;
    out[(size_t)node * OUT_SIZE + lane + 64] = o1;
}

extern "C" void kernel_launch(void* const* d_in, const int* in_sizes, int n_in,
                              void* d_out, int out_size, void* d_ws, size_t ws_size,
                              hipStream_t stream) {
    const float* x   = (const float*)d_in[0];
    const int*   ei  = (const int*)d_in[1];
    const float* ea  = (const float*)d_in[2];
    const float* Wq  = (const float*)d_in[3];
    const float* bq  = (const float*)d_in[4];
    const float* Wk  = (const float*)d_in[5];
    const float* bk  = (const float*)d_in[6];
    const float* Wv  = (const float*)d_in[7];
    const float* bv  = (const float*)d_in[8];
    const float* We  = (const float*)d_in[9];
    const float* be  = (const float*)d_in[10];
    const float* Ws  = (const float*)d_in[11];
    const float* bs  = (const float*)d_in[12];
    float* out = (float*)d_out;

    // workspace layout
    float* ws0 = (float*)d_ws;
    float* q   = ws0;                                  // 6.4M floats
    float* k   = q  + (size_t)N_NODES * OUT_SIZE;
    float* v   = k  + (size_t)N_NODES * OUT_SIZE;
    float* sk  = v  + (size_t)N_NODES * OUT_SIZE;
    float* q2  = sk + (size_t)N_NODES * OUT_SIZE;      // 3.2M
    float* qb  = q2 + (size_t)N_NODES * EDGE_DIM;      // 50K
    int* counts  = (int*)(qb + N_NODES);               // 50K
    int* incl    = counts  + N_NODES;                  // 50K
    int* bsum    = incl    + N_NODES;                  // NBLK
    int* rowptr  = bsum    + 256;                      // 50K+1
    int* cursor  = rowptr  + N_NODES + 1;              // 50K
    int* csr_src = cursor  + N_NODES;                  // 800K
    int* csr_eid = csr_src + N_EDGES;                  // 800K

    hipMemsetAsync(counts, 0, (size_t)N_NODES * sizeof(int), stream);

    // CSR build
    hist_kernel<<<(N_EDGES + 255) / 256, 256, 0, stream>>>(ei, counts);
    scan1_kernel<<<NBLK, SCAN_B, 0, stream>>>(counts, incl, bsum);
    scan2_kernel<<<1, SCAN_B, 0, stream>>>(bsum);
    scan3_kernel<<<NBLK, SCAN_B, 0, stream>>>(incl, bsum, counts, rowptr, cursor);
    scatter_kernel<<<(N_EDGES + 255) / 256, 256, 0, stream>>>(ei, cursor, csr_src, csr_eid);

    // projections
    dim3 gProj((N_NODES + 63) / 64, 4);
    proj_kernel<<<gProj, 256, 0, stream>>>(x, Wq, bq, Wk, bk, Wv, bv, Ws, bs,
                                           q, k, v, sk);
    q2_kernel<<<(N_NODES + 3) / 4, 256, 0, stream>>>(q, We, be, q2, qb);

    // fused edge phase + epilogue
    fused_kernel<<<(N_NODES + 3) / 4, 256, 0, stream>>>(
        rowptr, csr_src, csr_eid, q, k, v, q2, qb, ea, sk, We, be, out);
}

// Round 3
// 800.333 us; speedup vs baseline: 1.8947x; 1.2123x over previous
//
#include <hip/hip_runtime.h>
#include <hip/hip_bf16.h>
#include <math.h>

#define N_NODES 50000
#define N_EDGES 800000
#define IN_SIZE 256
#define OUT_SIZE 128
#define EDGE_DIM 64
#define WCAT 640   // [q:0-127 | k:128-255 | v:256-383 | sk:384-511 | q2:512-575 | pad]

#define SCAN_B 256
#define NBLK ((N_NODES + SCAN_B - 1) / SCAN_B)   // 196

__device__ __forceinline__ unsigned short f2bf(float f) {
    unsigned int u = __float_as_uint(f);
    unsigned int r = (u + 0x7fffu + ((u >> 16) & 1u)) >> 16;  // RNE
    return (unsigned short)r;
}
__device__ __forceinline__ float2 bf2_to_f2(unsigned int u) {
    float2 r;
    r.x = __uint_as_float(u << 16);
    r.y = __uint_as_float(u & 0xffff0000u);
    return r;
}

// ---------------- Wcat/bcat build ----------------
// grid (10, 256): blockIdx.y = k row, col = blockIdx.x*64 + tid
__global__ __launch_bounds__(64) void wcat_kernel(
    const float* __restrict__ Wq, const float* __restrict__ Wk,
    const float* __restrict__ Wv, const float* __restrict__ Ws,
    const float* __restrict__ We,
    const float* __restrict__ bq, const float* __restrict__ bk,
    const float* __restrict__ bv, const float* __restrict__ bs,
    float* __restrict__ Wcat, float* __restrict__ bcat)
{
    int kr  = blockIdx.y;
    int col = blockIdx.x * 64 + threadIdx.x;
    float w;
    if (col < 512) {
        int seg = col >> 7, c = col & 127;
        const float* W = (seg == 0) ? Wq : (seg == 1) ? Wk : (seg == 2) ? Wv : Ws;
        w = W[kr * OUT_SIZE + c];
    } else if (col < 576) {
        int d = col - 512;
        float acc = 0.f;
        #pragma unroll 8
        for (int c = 0; c < OUT_SIZE; c++)
            acc = fmaf(Wq[kr * OUT_SIZE + c], We[d * OUT_SIZE + c], acc);
        w = acc;
    } else {
        w = 0.f;
    }
    Wcat[kr * WCAT + col] = w;
    if (kr == 0) {
        float b;
        if (col < 512) {
            int seg = col >> 7, c = col & 127;
            const float* bb = (seg == 0) ? bq : (seg == 1) ? bk : (seg == 2) ? bv : bs;
            b = bb[c];
        } else if (col < 576) {
            int d = col - 512;
            float acc = 0.f;
            for (int c = 0; c < OUT_SIZE; c++)
                acc = fmaf(bq[c], We[d * OUT_SIZE + c], acc);
            b = acc;
        } else b = 0.f;
        bcat[col] = b;
    }
}

// ---------------- mega GEMM: [q|k|v|sk|q2] = x @ Wcat + bcat ----------------
// grid (391, 5), block 256, tile 128x128
__global__ __launch_bounds__(256) void gemm_kernel(
    const float* __restrict__ x, const float* __restrict__ Wcat,
    const float* __restrict__ bcat,
    float* __restrict__ qbuf, unsigned int* __restrict__ kbuf,
    unsigned int* __restrict__ vbuf, float* __restrict__ skbuf,
    float* __restrict__ q2buf)
{
    const int seg = blockIdx.y;
    const int n0  = seg * 128;
    const int m0  = blockIdx.x * 128;

    __shared__ __align__(16) float xs[128][33];
    __shared__ __align__(16) float ws[32][128];

    const int t  = threadIdx.x;
    const int tx = t & 15;    // col group: cols tx*8..tx*8+7
    const int ty = t >> 4;    // row group: rows ty*8..ty*8+7

    float acc[8][8];
    #pragma unroll
    for (int i = 0; i < 8; i++)
        #pragma unroll
        for (int j = 0; j < 8; j++) acc[i][j] = 0.f;

    for (int k0 = 0; k0 < IN_SIZE; k0 += 32) {
        #pragma unroll
        for (int r = 0; r < 4; r++) {
            int i   = t + 256 * r;
            int row = i >> 3;
            int c4  = i & 7;
            int gr  = m0 + row;
            float4 val = (gr < N_NODES)
                ? ((const float4*)(x + (size_t)gr * IN_SIZE + k0))[c4]
                : make_float4(0.f, 0.f, 0.f, 0.f);
            xs[row][c4 * 4 + 0] = val.x;
            xs[row][c4 * 4 + 1] = val.y;
            xs[row][c4 * 4 + 2] = val.z;
            xs[row][c4 * 4 + 3] = val.w;
        }
        #pragma unroll
        for (int r = 0; r < 4; r++) {
            int i  = t + 256 * r;
            int kr = i >> 5;
            int c4 = i & 31;
            float4 val = ((const float4*)(Wcat + (size_t)(k0 + kr) * WCAT + n0))[c4];
            ((float4*)&ws[kr][0])[c4] = val;
        }
        __syncthreads();
        #pragma unroll
        for (int kk = 0; kk < 32; kk++) {
            float xv[8], wv[8];
            #pragma unroll
            for (int i = 0; i < 8; i++) xv[i] = xs[ty * 8 + i][kk];
            #pragma unroll
            for (int j = 0; j < 8; j++) wv[j] = ws[kk][tx * 8 + j];
            #pragma unroll
            for (int i = 0; i < 8; i++)
                #pragma unroll
                for (int j = 0; j < 8; j++)
                    acc[i][j] = fmaf(xv[i], wv[j], acc[i][j]);
        }
        __syncthreads();
    }

    // epilogue
    #pragma unroll
    for (int i = 0; i < 8; i++) {
        int gr = m0 + ty * 8 + i;
        if (gr >= N_NODES) continue;
        float o[8];
        #pragma unroll
        for (int j = 0; j < 8; j++) o[j] = acc[i][j] + bcat[n0 + tx * 8 + j];
        if (seg == 1 || seg == 2) {
            // bf16 pack: 8 cols -> uint4
            unsigned int u[4];
            #pragma unroll
            for (int p = 0; p < 4; p++)
                u[p] = (unsigned int)f2bf(o[2 * p]) | ((unsigned int)f2bf(o[2 * p + 1]) << 16);
            unsigned int* dst = (seg == 1) ? kbuf : vbuf;
            uint4* d4 = (uint4*)(dst + (size_t)gr * 64 + tx * 4);
            *d4 = make_uint4(u[0], u[1], u[2], u[3]);
        } else if (seg == 0 || seg == 3) {
            float* dst = (seg == 0) ? qbuf : skbuf;
            float4* d4 = (float4*)(dst + (size_t)gr * OUT_SIZE + tx * 8);
            d4[0] = make_float4(o[0], o[1], o[2], o[3]);
            d4[1] = make_float4(o[4], o[5], o[6], o[7]);
        } else {
            int c = tx * 8;
            if (c < 64) {
                float4* d4 = (float4*)(q2buf + (size_t)gr * EDGE_DIM + c);
                d4[0] = make_float4(o[0], o[1], o[2], o[3]);
                d4[1] = make_float4(o[4], o[5], o[6], o[7]);
            }
        }
    }
}

// ---------------- CSR build ----------------
__global__ __launch_bounds__(256) void hist_kernel(
    const int* __restrict__ ei, int* __restrict__ counts)
{
    int e = blockIdx.x * 256 + threadIdx.x;
    if (e >= N_EDGES) return;
    atomicAdd(&counts[ei[N_EDGES + e]], 1);
}

__global__ __launch_bounds__(SCAN_B) void scan1_kernel(
    const int* __restrict__ counts, int* __restrict__ incl, int* __restrict__ bsum)
{
    __shared__ int tmp[SCAN_B];
    int i = blockIdx.x * SCAN_B + threadIdx.x;
    int val = (i < N_NODES) ? counts[i] : 0;
    tmp[threadIdx.x] = val;
    __syncthreads();
    for (int off = 1; off < SCAN_B; off <<= 1) {
        int t = (threadIdx.x >= off) ? tmp[threadIdx.x - off] : 0;
        __syncthreads();
        tmp[threadIdx.x] += t;
        __syncthreads();
    }
    if (i < N_NODES) incl[i] = tmp[threadIdx.x];
    if (threadIdx.x == SCAN_B - 1) bsum[blockIdx.x] = tmp[SCAN_B - 1];
}

__global__ __launch_bounds__(SCAN_B) void scan2_kernel(int* __restrict__ bsum)
{
    __shared__ int tmp[SCAN_B];
    int val = (threadIdx.x < NBLK) ? bsum[threadIdx.x] : 0;
    tmp[threadIdx.x] = val;
    __syncthreads();
    for (int off = 1; off < SCAN_B; off <<= 1) {
        int t = (threadIdx.x >= off) ? tmp[threadIdx.x - off] : 0;
        __syncthreads();
        tmp[threadIdx.x] += t;
        __syncthreads();
    }
    if (threadIdx.x < NBLK) bsum[threadIdx.x] = tmp[threadIdx.x];
}

__global__ __launch_bounds__(SCAN_B) void scan3_kernel(
    const int* __restrict__ incl, const int* __restrict__ bsum,
    const int* __restrict__ counts, int* __restrict__ rowptr, int* __restrict__ cursor)
{
    int i = blockIdx.x * SCAN_B + threadIdx.x;
    if (i >= N_NODES) return;
    int off = (blockIdx.x == 0) ? 0 : bsum[blockIdx.x - 1];
    int inc = incl[i] + off;
    rowptr[i + 1] = inc;
    cursor[i] = inc - counts[i];
    if (i == 0) rowptr[0] = 0;
}

__global__ __launch_bounds__(256) void scatter_kernel(
    const int* __restrict__ ei, int* __restrict__ cursor,
    int2* __restrict__ csr_se)
{
    int e = blockIdx.x * 256 + threadIdx.x;
    if (e >= N_EDGES) return;
    int dst = ei[N_EDGES + e];
    int pos = atomicAdd(&cursor[dst], 1);
    csr_se[pos] = make_int2(ei[e], e);
}

// ---------------- fused per-dst-node ----------------
__global__ __launch_bounds__(256) void fused_kernel(
    const int* __restrict__ rowptr, const int2* __restrict__ csr_se,
    const float* __restrict__ qbuf, const unsigned int* __restrict__ kbuf,
    const unsigned int* __restrict__ vbuf, const float* __restrict__ q2buf,
    const float* __restrict__ ea, const float* __restrict__ skbuf,
    const float* __restrict__ We, const float* __restrict__ be,
    float* __restrict__ out)
{
    int node = blockIdx.x * 4 + (threadIdx.x >> 6);
    if (node >= N_NODES) return;
    int lane = threadIdx.x & 63;
    int beg = rowptr[node];
    int end = rowptr[node + 1];

    float2 qv  = ((const float2*)qbuf)[(size_t)node * 64 + lane];
    float  q2v = q2buf[(size_t)node * EDGE_DIM + lane];
    float2 bev = ((const float2*)be)[lane];

    // qb = dot(q, be)
    float qbv = qv.x * bev.x + qv.y * bev.y;
    #pragma unroll
    for (int off = 32; off > 0; off >>= 1) qbv += __shfl_xor(qbv, off);

    const float scale = 0.08838834764831845f;  // 1/sqrt(128)
    float m = -INFINITY, l = 0.f;
    float ax = 0.f, ay = 0.f, a2 = 0.f;

    int i = beg;
    for (; i + 1 < end; i += 2) {
        int2 se1 = csr_se[i];
        int2 se2 = csr_se[i + 1];
        float2 k1 = bf2_to_f2(kbuf[(size_t)se1.x * 64 + lane]);
        float2 k2 = bf2_to_f2(kbuf[(size_t)se2.x * 64 + lane]);
        float2 v1 = bf2_to_f2(vbuf[(size_t)se1.x * 64 + lane]);
        float2 v2 = bf2_to_f2(vbuf[(size_t)se2.x * 64 + lane]);
        float ea1 = ea[(size_t)se1.y * EDGE_DIM + lane];
        float ea2 = ea[(size_t)se2.y * EDGE_DIM + lane];
        float p1 = qv.x * k1.x + qv.y * k1.y + q2v * ea1;
        float p2 = qv.x * k2.x + qv.y * k2.y + q2v * ea2;
        #pragma unroll
        for (int off = 32; off > 0; off >>= 1) p1 += __shfl_xor(p1, off);
        #pragma unroll
        for (int off = 32; off > 0; off >>= 1) p2 += __shfl_xor(p2, off);
        float s1 = (p1 + qbv) * scale;
        float s2 = (p2 + qbv) * scale;
        float mn = fmaxf(m, fmaxf(s1, s2));
        float sc  = __expf(m - mn);
        float pe1 = __expf(s1 - mn);
        float pe2 = __expf(s2 - mn);
        l  = l * sc + pe1 + pe2;
        ax = fmaf(ax, sc, fmaf(pe1, v1.x, pe2 * v2.x));
        ay = fmaf(ay, sc, fmaf(pe1, v1.y, pe2 * v2.y));
        a2 = fmaf(a2, sc, fmaf(pe1, ea1, pe2 * ea2));
        m = mn;
    }
    if (i < end) {
        int2 se1 = csr_se[i];
        float2 k1 = bf2_to_f2(kbuf[(size_t)se1.x * 64 + lane]);
        float2 v1 = bf2_to_f2(vbuf[(size_t)se1.x * 64 + lane]);
        float ea1 = ea[(size_t)se1.y * EDGE_DIM + lane];
        float p1 = qv.x * k1.x + qv.y * k1.y + q2v * ea1;
        #pragma unroll
        for (int off = 32; off > 0; off >>= 1) p1 += __shfl_xor(p1, off);
        float s1 = (p1 + qbv) * scale;
        float mn = fmaxf(m, s1);
        float sc  = __expf(m - mn);
        float pe1 = __expf(s1 - mn);
        l  = l * sc + pe1;
        ax = fmaf(ax, sc, pe1 * v1.x);
        ay = fmaf(ay, sc, pe1 * v1.y);
        a2 = fmaf(a2, sc, pe1 * ea1);
        m = mn;
    }

    float inv  = 1.f / (l + 1e-16f);
    float aggA = l * inv;
    ax *= inv; ay *= inv; a2 *= inv;

    float2 skv = ((const float2*)skbuf)[(size_t)node * 64 + lane];
    float ox = ax + aggA * bev.x + skv.x;
    float oy = ay + aggA * bev.y + skv.y;
    #pragma unroll 8
    for (int d = 0; d < EDGE_DIM; d++) {
        float g = __shfl(a2, d);
        float2 w = ((const float2*)We)[(size_t)d * 64 + lane];
        ox = fmaf(g, w.x, ox);
        oy = fmaf(g, w.y, oy);
    }
    ox = (ox > 0.f) ? ox : (__expf(ox) - 1.f);
    oy = (oy > 0.f) ? oy : (__expf(oy) - 1.f);
    ((float2*)out)[(size_t)node * 64 + lane] = make_float2(ox, oy);
}

extern "C" void kernel_launch(void* const* d_in, const int* in_sizes, int n_in,
                              void* d_out, int out_size, void* d_ws, size_t ws_size,
                              hipStream_t stream) {
    const float* x   = (const float*)d_in[0];
    const int*   ei  = (const int*)d_in[1];
    const float* ea  = (const float*)d_in[2];
    const float* Wq  = (const float*)d_in[3];
    const float* bq  = (const float*)d_in[4];
    const float* Wk  = (const float*)d_in[5];
    const float* bk  = (const float*)d_in[6];
    const float* Wv  = (const float*)d_in[7];
    const float* bv  = (const float*)d_in[8];
    const float* We  = (const float*)d_in[9];
    const float* be  = (const float*)d_in[10];
    const float* Ws  = (const float*)d_in[11];
    const float* bs  = (const float*)d_in[12];
    float* out = (float*)d_out;

    // workspace layout (float units)
    float* ws0   = (float*)d_ws;
    float* qbuf  = ws0;                                   // 6.4M
    float* skbuf = qbuf  + (size_t)N_NODES * OUT_SIZE;    // 6.4M
    float* q2buf = skbuf + (size_t)N_NODES * OUT_SIZE;    // 3.2M
    unsigned int* kbuf = (unsigned int*)(q2buf + (size_t)N_NODES * EDGE_DIM); // 3.2M u32
    unsigned int* vbuf = kbuf + (size_t)N_NODES * 64;     // 3.2M u32
    float* Wcat  = (float*)(vbuf + (size_t)N_NODES * 64); // 163840
    float* bcat  = Wcat + 256 * WCAT;                     // 640
    int* counts  = (int*)(bcat + WCAT);                   // 50K
    int* incl    = counts + N_NODES;
    int* bsum    = incl + N_NODES;                        // 256
    int* rowptr  = bsum + 256;                            // 50K+1
    int* cursor  = rowptr + N_NODES + 1;                  // 50K
    int* pad     = cursor + N_NODES;                      // align to 8B
    int2* csr_se = (int2*)(pad + 1);                      // 800K int2

    hipMemsetAsync(counts, 0, (size_t)N_NODES * sizeof(int), stream);

    // CSR build
    hist_kernel<<<(N_EDGES + 255) / 256, 256, 0, stream>>>(ei, counts);
    scan1_kernel<<<NBLK, SCAN_B, 0, stream>>>(counts, incl, bsum);
    scan2_kernel<<<1, SCAN_B, 0, stream>>>(bsum);
    scan3_kernel<<<NBLK, SCAN_B, 0, stream>>>(incl, bsum, counts, rowptr, cursor);
    scatter_kernel<<<(N_EDGES + 255) / 256, 256, 0, stream>>>(ei, cursor, csr_se);

    // weights
    dim3 gW(10, 256);
    wcat_kernel<<<gW, 64, 0, stream>>>(Wq, Wk, Wv, Ws, We, bq, bk, bv, bs, Wcat, bcat);

    // mega GEMM
    dim3 gG((N_NODES + 127) / 128, 5);
    gemm_kernel<<<gG, 256, 0, stream>>>(x, Wcat, bcat, qbuf, kbuf, vbuf, skbuf, q2buf);

    // fused edge phase + epilogue
    fused_kernel<<<(N_NODES + 3) / 4, 256, 0, stream>>>(
        rowptr, csr_se, qbuf, kbuf, vbuf, q2buf, ea, skbuf, We, be, out);
}

// Round 4
// 634.094 us; speedup vs baseline: 2.3914x; 1.2622x over previous
//
#include <hip/hip_runtime.h>
#include <hip/hip_bf16.h>
#include <math.h>

#define N_NODES 50000
#define N_EDGES 800000
#define IN_SIZE 256
#define OUT_SIZE 128
#define EDGE_DIM 64
#define NCAT 576   // [q:0-127 | k:128-255 | v:256-383 | sk:384-511 | q2:512-575]

#define SCAN_B 256
#define NBLK ((N_NODES + SCAN_B - 1) / SCAN_B)   // 196

typedef __attribute__((ext_vector_type(8))) short short8;
typedef __attribute__((ext_vector_type(4))) float floatx4;

#define GPTR(p) ((const __attribute__((address_space(1))) void*)(p))
#define LPTR(p) ((__attribute__((address_space(3))) void*)(p))

__device__ __forceinline__ unsigned short f2bf(float f) {
    unsigned int u = __float_as_uint(f);
    unsigned int r = (u + 0x7fffu + ((u >> 16) & 1u)) >> 16;  // RNE
    return (unsigned short)r;
}
__device__ __forceinline__ float2 bf2_to_f2(unsigned int u) {
    float2 r;
    r.x = __uint_as_float(u << 16);
    r.y = __uint_as_float(u & 0xffff0000u);
    return r;
}

// ---------------- x -> bf16 ----------------
__global__ __launch_bounds__(256) void xcast_kernel(
    const float* __restrict__ x, unsigned short* __restrict__ xb)
{
    size_t i = ((size_t)blockIdx.x * 256 + threadIdx.x) * 4;
    float4 v = *(const float4*)(x + i);
    uint2 p;
    p.x = (unsigned int)f2bf(v.x) | ((unsigned int)f2bf(v.y) << 16);
    p.y = (unsigned int)f2bf(v.z) | ((unsigned int)f2bf(v.w) << 16);
    *(uint2*)(xb + i) = p;
}

// ---------------- WcatT (bf16, transposed [NCAT][256]) + bcat ----------------
// grid = NCAT blocks, 256 threads (thread = k-row)
__global__ __launch_bounds__(256) void wcat_kernel(
    const float* __restrict__ Wq, const float* __restrict__ Wk,
    const float* __restrict__ Wv, const float* __restrict__ Ws,
    const float* __restrict__ We,
    const float* __restrict__ bq, const float* __restrict__ bk,
    const float* __restrict__ bv, const float* __restrict__ bs,
    unsigned short* __restrict__ WcatT, float* __restrict__ bcat)
{
    int col = blockIdx.x;
    int kr  = threadIdx.x;
    float w;
    if (col < 512) {
        int s = col >> 7, c = col & 127;
        const float* W = (s == 0) ? Wq : (s == 1) ? Wk : (s == 2) ? Wv : Ws;
        w = W[kr * OUT_SIZE + c];
    } else {
        int d = col - 512;
        float a = 0.f;
        #pragma unroll 8
        for (int c = 0; c < OUT_SIZE; c++)
            a = fmaf(Wq[kr * OUT_SIZE + c], We[d * OUT_SIZE + c], a);
        w = a;
    }
    WcatT[(size_t)col * 256 + kr] = f2bf(w);
    if (kr == 0) {
        float b;
        if (col < 512) {
            int s = col >> 7, c = col & 127;
            b = ((s == 0) ? bq : (s == 1) ? bk : (s == 2) ? bv : bs)[c];
        } else {
            int d = col - 512;
            b = 0.f;
            for (int c = 0; c < OUT_SIZE; c++)
                b = fmaf(bq[c], We[d * OUT_SIZE + c], b);
        }
        bcat[col] = b;
    }
}

// ---------------- MFMA mega GEMM: [q|k|v|sk|q2] = xb @ WcatT^T + bcat ----------------
// grid (391, 9), block 256. Per block: 128 rows x 64 cols, BK=32, K=256.
__global__ __launch_bounds__(256) void gemm_kernel(
    const unsigned short* __restrict__ xb,     // [N_NODES][256] bf16
    const unsigned short* __restrict__ WcatT,  // [NCAT][256] bf16
    const float* __restrict__ bcat,
    float* __restrict__ qbuf, unsigned short* __restrict__ kb16,
    unsigned short* __restrict__ vb16, float* __restrict__ skbuf,
    float* __restrict__ q2buf)
{
    __shared__ __align__(16) unsigned short Als[128 * 32];  // [row][32]
    __shared__ __align__(16) unsigned short Bls[64 * 32];   // [n][32]

    const int t    = threadIdx.x;
    const int wave = t >> 6;
    const int lane = t & 63;
    const int quad = lane >> 4;
    const int l16  = lane & 15;

    const int m0 = blockIdx.x * 128;
    const int n0 = blockIdx.y * 64;

    floatx4 acc[2][4];
    #pragma unroll
    for (int mt = 0; mt < 2; mt++)
        #pragma unroll
        for (int nt = 0; nt < 4; nt++)
            acc[mt][nt] = (floatx4){0.f, 0.f, 0.f, 0.f};

    for (int k0 = 0; k0 < IN_SIZE; k0 += 32) {
        if (k0) __syncthreads();
        // stage A: 128 rows x 32 bf16 (64 B/row) = 512 x 16B chunks, 2 rounds
        #pragma unroll
        for (int r = 0; r < 2; r++) {
            int idx = r * 256 + t;
            int row = idx >> 2;
            int c8  = idx & 3;
            int grow = m0 + row;
            if (grow >= N_NODES) grow = N_NODES - 1;
            const unsigned short* g = xb + (size_t)grow * IN_SIZE + k0 + c8 * 8;
            __builtin_amdgcn_global_load_lds(GPTR(g), LPTR(Als + (size_t)(r * 256 + wave * 64) * 8), 16, 0, 0);
        }
        // stage B: 64 n-rows x 32 bf16 = 256 x 16B chunks, 1 round
        {
            int n  = t >> 2;
            int c8 = t & 3;
            const unsigned short* g = WcatT + (size_t)(n0 + n) * 256 + k0 + c8 * 8;
            __builtin_amdgcn_global_load_lds(GPTR(g), LPTR(Bls + (size_t)(wave * 64) * 8), 16, 0, 0);
        }
        __syncthreads();

        short8 af[2], bf[4];
        #pragma unroll
        for (int mt = 0; mt < 2; mt++)
            af[mt] = *(const short8*)(Als + (size_t)(wave * 32 + mt * 16 + l16) * 32 + quad * 8);
        #pragma unroll
        for (int nt = 0; nt < 4; nt++)
            bf[nt] = *(const short8*)(Bls + (size_t)(nt * 16 + l16) * 32 + quad * 8);
        #pragma unroll
        for (int mt = 0; mt < 2; mt++)
            #pragma unroll
            for (int nt = 0; nt < 4; nt++)
                acc[mt][nt] = __builtin_amdgcn_mfma_f32_16x16x32_bf16(af[mt], bf[nt], acc[mt][nt], 0, 0, 0);
    }

    // epilogue: C/D layout col=lane&15, row=quad*4+reg
    const int seg = blockIdx.y;  // 0,1:q  2,3:k  4,5:v  6,7:sk  8:q2
    #pragma unroll
    for (int mt = 0; mt < 2; mt++) {
        #pragma unroll
        for (int r = 0; r < 4; r++) {
            int row = m0 + wave * 32 + mt * 16 + quad * 4 + r;
            if (row >= N_NODES) continue;
            #pragma unroll
            for (int nt = 0; nt < 4; nt++) {
                int c = n0 + nt * 16 + l16;
                float val = acc[mt][nt][r] + bcat[c];
                if (seg < 2)      qbuf[(size_t)row * OUT_SIZE + c] = val;
                else if (seg < 4) kb16[(size_t)row * OUT_SIZE + (c - 128)] = f2bf(val);
                else if (seg < 6) vb16[(size_t)row * OUT_SIZE + (c - 256)] = f2bf(val);
                else if (seg < 8) skbuf[(size_t)row * OUT_SIZE + (c - 384)] = val;
                else              q2buf[(size_t)row * EDGE_DIM + (c - 512)] = val;
            }
        }
    }
}

// ---------------- CSR build ----------------
__global__ __launch_bounds__(256) void hist_kernel(
    const int* __restrict__ ei, int* __restrict__ counts)
{
    int e = blockIdx.x * 256 + threadIdx.x;
    if (e >= N_EDGES) return;
    atomicAdd(&counts[ei[N_EDGES + e]], 1);
}

__global__ __launch_bounds__(SCAN_B) void scan1_kernel(
    const int* __restrict__ counts, int* __restrict__ incl, int* __restrict__ bsum)
{
    __shared__ int tmp[SCAN_B];
    int i = blockIdx.x * SCAN_B + threadIdx.x;
    int val = (i < N_NODES) ? counts[i] : 0;
    tmp[threadIdx.x] = val;
    __syncthreads();
    for (int off = 1; off < SCAN_B; off <<= 1) {
        int t = (threadIdx.x >= off) ? tmp[threadIdx.x - off] : 0;
        __syncthreads();
        tmp[threadIdx.x] += t;
        __syncthreads();
    }
    if (i < N_NODES) incl[i] = tmp[threadIdx.x];
    if (threadIdx.x == SCAN_B - 1) bsum[blockIdx.x] = tmp[SCAN_B - 1];
}

__global__ __launch_bounds__(SCAN_B) void scan2_kernel(int* __restrict__ bsum)
{
    __shared__ int tmp[SCAN_B];
    int val = (threadIdx.x < NBLK) ? bsum[threadIdx.x] : 0;
    tmp[threadIdx.x] = val;
    __syncthreads();
    for (int off = 1; off < SCAN_B; off <<= 1) {
        int t = (threadIdx.x >= off) ? tmp[threadIdx.x - off] : 0;
        __syncthreads();
        tmp[threadIdx.x] += t;
        __syncthreads();
    }
    if (threadIdx.x < NBLK) bsum[threadIdx.x] = tmp[threadIdx.x];
}

__global__ __launch_bounds__(SCAN_B) void scan3_kernel(
    const int* __restrict__ incl, const int* __restrict__ bsum,
    const int* __restrict__ counts, int* __restrict__ rowptr, int* __restrict__ cursor)
{
    int i = blockIdx.x * SCAN_B + threadIdx.x;
    if (i >= N_NODES) return;
    int off = (blockIdx.x == 0) ? 0 : bsum[blockIdx.x - 1];
    int inc = incl[i] + off;
    rowptr[i + 1] = inc;
    cursor[i] = inc - counts[i];
    if (i == 0) rowptr[0] = 0;
}

__global__ __launch_bounds__(256) void scatter_kernel(
    const int* __restrict__ ei, int* __restrict__ cursor,
    int2* __restrict__ csr_se)
{
    int e = blockIdx.x * 256 + threadIdx.x;
    if (e >= N_EDGES) return;
    int dst = ei[N_EDGES + e];
    int pos = atomicAdd(&cursor[dst], 1);
    csr_se[pos] = make_int2(ei[e], e);
}

// ---------------- fused per-dst-node ----------------
__global__ __launch_bounds__(256) void fused_kernel(
    const int* __restrict__ rowptr, const int2* __restrict__ csr_se,
    const float* __restrict__ qbuf, const unsigned int* __restrict__ kbuf,
    const unsigned int* __restrict__ vbuf, const float* __restrict__ q2buf,
    const float* __restrict__ ea, const float* __restrict__ skbuf,
    const float* __restrict__ We, const float* __restrict__ be,
    float* __restrict__ out)
{
    int node = blockIdx.x * 4 + (threadIdx.x >> 6);
    if (node >= N_NODES) return;
    int lane = threadIdx.x & 63;
    int beg = rowptr[node];
    int end = rowptr[node + 1];

    float2 qv  = ((const float2*)qbuf)[(size_t)node * 64 + lane];
    float  q2v = q2buf[(size_t)node * EDGE_DIM + lane];
    float2 bev = ((const float2*)be)[lane];

    float qbv = qv.x * bev.x + qv.y * bev.y;
    #pragma unroll
    for (int off = 32; off > 0; off >>= 1) qbv += __shfl_xor(qbv, off);

    const float scale = 0.08838834764831845f;  // 1/sqrt(128)
    float m = -INFINITY, l = 0.f;
    float ax = 0.f, ay = 0.f, a2 = 0.f;

    int i = beg;
    for (; i + 1 < end; i += 2) {
        int2 se1 = csr_se[i];
        int2 se2 = csr_se[i + 1];
        float2 k1 = bf2_to_f2(kbuf[(size_t)se1.x * 64 + lane]);
        float2 k2 = bf2_to_f2(kbuf[(size_t)se2.x * 64 + lane]);
        float2 v1 = bf2_to_f2(vbuf[(size_t)se1.x * 64 + lane]);
        float2 v2 = bf2_to_f2(vbuf[(size_t)se2.x * 64 + lane]);
        float ea1 = ea[(size_t)se1.y * EDGE_DIM + lane];
        float ea2 = ea[(size_t)se2.y * EDGE_DIM + lane];
        float p1 = qv.x * k1.x + qv.y * k1.y + q2v * ea1;
        float p2 = qv.x * k2.x + qv.y * k2.y + q2v * ea2;
        #pragma unroll
        for (int off = 32; off > 0; off >>= 1) p1 += __shfl_xor(p1, off);
        #pragma unroll
        for (int off = 32; off > 0; off >>= 1) p2 += __shfl_xor(p2, off);
        float s1 = (p1 + qbv) * scale;
        float s2 = (p2 + qbv) * scale;
        float mn = fmaxf(m, fmaxf(s1, s2));
        float sc  = __expf(m - mn);
        float pe1 = __expf(s1 - mn);
        float pe2 = __expf(s2 - mn);
        l  = l * sc + pe1 + pe2;
        ax = fmaf(ax, sc, fmaf(pe1, v1.x, pe2 * v2.x));
        ay = fmaf(ay, sc, fmaf(pe1, v1.y, pe2 * v2.y));
        a2 = fmaf(a2, sc, fmaf(pe1, ea1, pe2 * ea2));
        m = mn;
    }
    if (i < end) {
        int2 se1 = csr_se[i];
        float2 k1 = bf2_to_f2(kbuf[(size_t)se1.x * 64 + lane]);
        float2 v1 = bf2_to_f2(vbuf[(size_t)se1.x * 64 + lane]);
        float ea1 = ea[(size_t)se1.y * EDGE_DIM + lane];
        float p1 = qv.x * k1.x + qv.y * k1.y + q2v * ea1;
        #pragma unroll
        for (int off = 32; off > 0; off >>= 1) p1 += __shfl_xor(p1, off);
        float s1 = (p1 + qbv) * scale;
        float mn = fmaxf(m, s1);
        float sc  = __expf(m - mn);
        float pe1 = __expf(s1 - mn);
        l  = l * sc + pe1;
        ax = fmaf(ax, sc, pe1 * v1.x);
        ay = fmaf(ay, sc, pe1 * v1.y);
        a2 = fmaf(a2, sc, pe1 * ea1);
        m = mn;
    }

    float inv  = 1.f / (l + 1e-16f);
    float aggA = l * inv;
    ax *= inv; ay *= inv; a2 *= inv;

    float2 skv = ((const float2*)skbuf)[(size_t)node * 64 + lane];
    float ox = ax + aggA * bev.x + skv.x;
    float oy = ay + aggA * bev.y + skv.y;
    #pragma unroll 8
    for (int d = 0; d < EDGE_DIM; d++) {
        float g = __shfl(a2, d);
        float2 w = ((const float2*)We)[(size_t)d * 64 + lane];
        ox = fmaf(g, w.x, ox);
        oy = fmaf(g, w.y, oy);
    }
    ox = (ox > 0.f) ? ox : (__expf(ox) - 1.f);
    oy = (oy > 0.f) ? oy : (__expf(oy) - 1.f);
    ((float2*)out)[(size_t)node * 64 + lane] = make_float2(ox, oy);
}

extern "C" void kernel_launch(void* const* d_in, const int* in_sizes, int n_in,
                              void* d_out, int out_size, void* d_ws, size_t ws_size,
                              hipStream_t stream) {
    const float* x   = (const float*)d_in[0];
    const int*   ei  = (const int*)d_in[1];
    const float* ea  = (const float*)d_in[2];
    const float* Wq  = (const float*)d_in[3];
    const float* bq  = (const float*)d_in[4];
    const float* Wk  = (const float*)d_in[5];
    const float* bk  = (const float*)d_in[6];
    const float* Wv  = (const float*)d_in[7];
    const float* bv  = (const float*)d_in[8];
    const float* We  = (const float*)d_in[9];
    const float* be  = (const float*)d_in[10];
    const float* Ws  = (const float*)d_in[11];
    const float* bs  = (const float*)d_in[12];
    float* out = (float*)d_out;

    // workspace layout
    float* ws0   = (float*)d_ws;
    float* qbuf  = ws0;                                     // 6.4M f
    float* skbuf = qbuf  + (size_t)N_NODES * OUT_SIZE;      // 6.4M f
    float* q2buf = skbuf + (size_t)N_NODES * OUT_SIZE;      // 3.2M f
    unsigned short* kb16 = (unsigned short*)(q2buf + (size_t)N_NODES * EDGE_DIM); // 6.4M sh
    unsigned short* vb16 = kb16 + (size_t)N_NODES * OUT_SIZE;                     // 6.4M sh
    unsigned short* xb   = vb16 + (size_t)N_NODES * OUT_SIZE;                     // 12.8M sh
    unsigned short* WcatT = xb + (size_t)N_NODES * IN_SIZE;                       // 147456 sh
    float* bcat  = (float*)(WcatT + (size_t)NCAT * 256);    // 576 f
    int* counts  = (int*)(bcat + NCAT);                     // 50K
    int* incl    = counts + N_NODES;
    int* bsum    = incl + N_NODES;                          // 256
    int* rowptr  = bsum + 256;                              // 50K+1
    int* cursor  = rowptr + N_NODES + 1;                    // 50K
    int2* csr_se = (int2*)(cursor + N_NODES + 1);           // 800K int2 (8B aligned)

    hipMemsetAsync(counts, 0, (size_t)N_NODES * sizeof(int), stream);

    // CSR build
    hist_kernel<<<(N_EDGES + 255) / 256, 256, 0, stream>>>(ei, counts);
    scan1_kernel<<<NBLK, SCAN_B, 0, stream>>>(counts, incl, bsum);
    scan2_kernel<<<1, SCAN_B, 0, stream>>>(bsum);
    scan3_kernel<<<NBLK, SCAN_B, 0, stream>>>(incl, bsum, counts, rowptr, cursor);
    scatter_kernel<<<(N_EDGES + 255) / 256, 256, 0, stream>>>(ei, cursor, csr_se);

    // bf16 conversions / weights
    xcast_kernel<<<(N_NODES * IN_SIZE / 4 + 255) / 256, 256, 0, stream>>>(x, xb);
    wcat_kernel<<<NCAT, 256, 0, stream>>>(Wq, Wk, Wv, Ws, We, bq, bk, bv, bs, WcatT, bcat);

    // MFMA mega GEMM
    dim3 gG((N_NODES + 127) / 128, 9);
    gemm_kernel<<<gG, 256, 0, stream>>>(xb, WcatT, bcat, qbuf, kb16, vb16, skbuf, q2buf);

    // fused edge phase + epilogue
    fused_kernel<<<(N_NODES + 3) / 4, 256, 0, stream>>>(
        rowptr, csr_se, qbuf, (const unsigned int*)kb16, (const unsigned int*)vb16,
        q2buf, ea, skbuf, We, be, out);
}